// Round 3
// 596.051 us; speedup vs baseline: 1.1715x; 1.1715x over previous
//
#include <hip/hip_runtime.h>
#include <math.h>

typedef __bf16 bf16x8 __attribute__((ext_vector_type(8)));
typedef __bf16 bf16x4 __attribute__((ext_vector_type(4)));
typedef float f32x4 __attribute__((ext_vector_type(4)));

__device__ __forceinline__ void atomAdd(float* p, float v) {
#if __has_builtin(__builtin_amdgcn_global_atomic_fadd_f32)
    unsafeAtomicAdd(p, v);
#else
    atomicAdd(p, v);
#endif
}

// 8 consecutive fp32 -> bf16x8 via native RNE casts (compiler emits v_cvt_pk_bf16_f32)
__device__ __forceinline__ bf16x8 cvt8(const float* p) {
    f32x4 lo = *reinterpret_cast<const f32x4*>(p);
    f32x4 hi = *reinterpret_cast<const f32x4*>(p + 4);
    bf16x8 r;
#pragma unroll
    for (int i = 0; i < 4; ++i) { r[i] = (__bf16)lo[i]; r[i + 4] = (__bf16)hi[i]; }
    return r;
}

// ---------------------------------------------------------------------------
// K-split accumulating GEMM:  out[m,n] += sum_{k in chunk} A[m,k]*W[n,k]
// A: [64,K] bf16 row-major (pre-converted). W: [N,K] fp32 row-major.
// out fp32, pre-initialized with bias; accumulated via atomics.
// Block = 256 threads = 4 independent waves, wave w owns n-tile 4*bx+w.
// grid = (N/64, K/KC, layers). MFMA 16x16x32 bf16.
// C/D: col = lane&15 (n), row = quad*4 + reg (m).
// ---------------------------------------------------------------------------
__global__ __launch_bounds__(256) void gemm_acc(
    const __bf16* __restrict__ A, long long Asb,
    const float* __restrict__ W, long long Wsb,
    float* __restrict__ out, long long osb,
    int K, int KC, int N)
{
    const int l = threadIdx.x & 63;
    const int wave = threadIdx.x >> 6;
    const int lane16 = l & 15;
    const int quad = l >> 4;
    const int layer = blockIdx.z;
    const int n = (blockIdx.x * 4 + wave) * 16 + lane16;
    const int k0 = blockIdx.y * KC;

    A += (long long)layer * Asb + k0 + quad * 8;
    const float* wp = W + (long long)layer * Wsb + (long long)n * K + k0 + quad * 8;
    const __bf16* ap0 = A + (long long)(lane16 +  0) * K;
    const __bf16* ap1 = A + (long long)(lane16 + 16) * K;
    const __bf16* ap2 = A + (long long)(lane16 + 32) * K;
    const __bf16* ap3 = A + (long long)(lane16 + 48) * K;

    f32x4 acc0 = {0.f, 0.f, 0.f, 0.f};
    f32x4 acc1 = acc0, acc2 = acc0, acc3 = acc0;

#pragma unroll 4
    for (int k = 0; k < KC; k += 32) {
        bf16x8 b  = cvt8(wp + k);
        bf16x8 a0 = *reinterpret_cast<const bf16x8*>(ap0 + k);
        bf16x8 a1 = *reinterpret_cast<const bf16x8*>(ap1 + k);
        bf16x8 a2 = *reinterpret_cast<const bf16x8*>(ap2 + k);
        bf16x8 a3 = *reinterpret_cast<const bf16x8*>(ap3 + k);
        acc0 = __builtin_amdgcn_mfma_f32_16x16x32_bf16(a0, b, acc0, 0, 0, 0);
        acc1 = __builtin_amdgcn_mfma_f32_16x16x32_bf16(a1, b, acc1, 0, 0, 0);
        acc2 = __builtin_amdgcn_mfma_f32_16x16x32_bf16(a2, b, acc2, 0, 0, 0);
        acc3 = __builtin_amdgcn_mfma_f32_16x16x32_bf16(a3, b, acc3, 0, 0, 0);
    }

    f32x4 accs[4] = {acc0, acc1, acc2, acc3};
    float* ob = out + (long long)layer * osb + n;
#pragma unroll
    for (int mt = 0; mt < 4; ++mt)
#pragma unroll
        for (int r = 0; r < 4; ++r) {
            const int m = mt * 16 + quad * 4 + r;
            atomAdd(ob + (long long)m * N, accs[mt][r]);
        }
}

// fp32 -> bf16 convert, optional relu, optional fp32 residual add; vec4/thread
template <int RELU, int RES>
__global__ __launch_bounds__(256) void conv_bf(
    const float* __restrict__ in, const float* __restrict__ res,
    __bf16* __restrict__ out, int total4)
{
    const int gid = blockIdx.x * 256 + threadIdx.x;
    if (gid >= total4) return;
    f32x4 v = reinterpret_cast<const f32x4*>(in)[gid];
    f32x4 rv;
    if (RES) rv = reinterpret_cast<const f32x4*>(res)[gid];
    bf16x4 o;
#pragma unroll
    for (int i = 0; i < 4; ++i) {
        float a = v[i];
        if (RELU) a = fmaxf(a, 0.0f);
        if (RES) a += rv[i];
        o[i] = (__bf16)a;
    }
    reinterpret_cast<bf16x4*>(out)[gid] = o;
}

// Pre-initialize all fp32 accumulators with biases.
// Ranges (elems): t0 64x1024 | a1b | a2b | attnb | gh 8x64x3072 |
//                 gi 8x64x3072 | logp 64x32000
__global__ __launch_bounds__(256) void init_acc(
    const float* __restrict__ map_b,
    const float* __restrict__ ai_b, const float* __restrict__ ah_b,
    const float* __restrict__ ao_b, const float* __restrict__ gru_bhh,
    const float* __restrict__ gru_bih, const float* __restrict__ out_b,
    float* __restrict__ t0, float* __restrict__ a1b, float* __restrict__ a2b,
    float* __restrict__ attnb, float* __restrict__ gh, float* __restrict__ gi,
    float* __restrict__ logp)
{
    int idx = blockIdx.x * 256 + threadIdx.x;  // 5455872 total
    if (idx < 65536) { t0[idx] = map_b[idx & 1023]; return; }
    idx -= 65536;
    if (idx < 65536) { a1b[idx] = ai_b[idx & 1023]; return; }
    idx -= 65536;
    if (idx < 65536) { a2b[idx] = ah_b[idx & 1023]; return; }
    idx -= 65536;
    if (idx < 65536) { attnb[idx] = ao_b[idx & 1023]; return; }
    idx -= 65536;
    if (idx < 1572864) {
        const int layer = idx / 196608, col = idx % 3072;
        gh[idx] = gru_bhh[layer * 3072 + col];
        return;
    }
    idx -= 1572864;
    if (idx < 1572864) {
        const int layer = idx / 196608, col = idx % 3072;
        gi[idx] = gru_bih[layer * 3072 + col];
        return;
    }
    idx -= 1572864;
    if (idx < 2048000) logp[idx] = out_b[idx % 32000];
}

// xe = bf16(relu(emb[x]))  -> [64,1024] bf16, vec4/thread
__global__ __launch_bounds__(256) void gather_relu(
    const float* __restrict__ emb, const int* __restrict__ xidx,
    __bf16* __restrict__ xe)
{
    const int gid = blockIdx.x * 256 + threadIdx.x;  // 16384 total
    const int m = gid >> 8, e = (gid & 255) << 2;
    f32x4 v = *reinterpret_cast<const f32x4*>(emb + (long long)xidx[m] * 1024 + e);
    bf16x4 o;
#pragma unroll
    for (int i = 0; i < 4; ++i) o[i] = (__bf16)fmaxf(v[i], 0.0f);
    *reinterpret_cast<bf16x4*>(xe + ((long long)m << 10) + e) = o;
}

// hbf[i] = bf16(hiddens[i] + relu(attnb))  -> [8,64,1024] bf16, vec4/thread
__global__ __launch_bounds__(256) void hsum(
    const float* __restrict__ hiddens, const float* __restrict__ attn,
    __bf16* __restrict__ hbf)
{
    const int gid = blockIdx.x * 256 + threadIdx.x;  // 131072 vec4 total
    f32x4 hv = reinterpret_cast<const f32x4*>(hiddens)[gid];
    f32x4 av = reinterpret_cast<const f32x4*>(attn)[gid & 16383];
    bf16x4 o;
#pragma unroll
    for (int i = 0; i < 4; ++i) o[i] = (__bf16)(hv[i] + fmaxf(av[i], 0.0f));
    reinterpret_cast<bf16x4*>(hbf)[gid] = o;
}

// GRU pointwise; h = hiddens + relu(attn) recomputed in fp32 (exact as before).
// Writes cell output fp32 (and h1 copy for c==0) and next GEMM input in bf16.
__global__ __launch_bounds__(256) void gru_pw(
    const float* __restrict__ gi, const float* __restrict__ gh,
    const float* __restrict__ hiddens, const float* __restrict__ attn,
    const float* __restrict__ oprev,
    float* __restrict__ o_out, float* __restrict__ o_out2,
    __bf16* __restrict__ xin_next)
{
    const int gid = blockIdx.x * 256 + threadIdx.x;  // 65536 total
    const int m = gid >> 10, nn = gid & 1023;
    const long long gb = (long long)m * 3072 + nn;
    const float i_r = gi[gb], i_z = gi[gb + 1024], i_n = gi[gb + 2048];
    const float h_r = gh[gb], h_z = gh[gb + 1024], h_n = gh[gb + 2048];
    const float r = 1.0f / (1.0f + __expf(-(i_r + h_r)));
    const float z = 1.0f / (1.0f + __expf(-(i_z + h_z)));
    const float nv = tanhf(i_n + r * h_n);
    const float hcur = hiddens[gid] + fmaxf(attn[gid], 0.0f);
    const float x = (1.0f - z) * nv + z * hcur;
    o_out[gid] = x;
    if (o_out2) o_out2[gid] = x;
    float xi = x;
    if (oprev) xi += oprev[gid];
    xin_next[gid] = (__bf16)xi;
}

// per-row logsumexp over [64,32000] fp32 logits, float4 loads
__global__ __launch_bounds__(256) void rowstats(
    const float* __restrict__ logits, float* __restrict__ stats)
{
    const int m = blockIdx.x;
    const f32x4* row = reinterpret_cast<const f32x4*>(logits + (long long)m * 32000);
    __shared__ float red[256];
    const int tid = threadIdx.x;
    float mx = -1e30f;
    for (int i = tid; i < 8000; i += 256) {
        f32x4 v = row[i];
        mx = fmaxf(mx, fmaxf(fmaxf(v[0], v[1]), fmaxf(v[2], v[3])));
    }
    red[tid] = mx;
    __syncthreads();
    for (int off = 128; off > 0; off >>= 1) {
        if (tid < off) red[tid] = fmaxf(red[tid], red[tid + off]);
        __syncthreads();
    }
    mx = red[0];
    __syncthreads();
    float s = 0.0f;
    for (int i = tid; i < 8000; i += 256) {
        f32x4 v = row[i];
        s += __expf(v[0] - mx) + __expf(v[1] - mx) + __expf(v[2] - mx) + __expf(v[3] - mx);
    }
    red[tid] = s;
    __syncthreads();
    for (int off = 128; off > 0; off >>= 1) {
        if (tid < off) red[tid] += red[tid + off];
        __syncthreads();
    }
    if (tid == 0) stats[m] = mx + logf(red[0]);
}

// in-place: logp = logits - stats[m]
__global__ __launch_bounds__(256) void logp_k(
    float* __restrict__ out, const float* __restrict__ stats)
{
    const int n = blockIdx.x * 256 + threadIdx.x;  // gridDim.x = 125
    const int m = blockIdx.y;
    const long long idx = (long long)m * 32000 + n;
    out[idx] = out[idx] - stats[m];
}

extern "C" void kernel_launch(void* const* d_in, const int* in_sizes, int n_in,
                              void* d_out, int out_size, void* d_ws, size_t ws_size,
                              hipStream_t stream)
{
    const float* feature   = (const float*)d_in[0];   // [64,2048]
    const int*   x         = (const int*)d_in[1];     // [64]
    const float* attention = (const float*)d_in[2];   // [64,1024]
    const float* hiddens   = (const float*)d_in[3];   // [8,64,1024]
    const float* emb       = (const float*)d_in[4];   // [32000,1024]
    const float* map_W     = (const float*)d_in[5];   // [1024,2048]
    const float* map_b     = (const float*)d_in[6];
    const float* ai_W      = (const float*)d_in[7];
    const float* ai_b      = (const float*)d_in[8];
    const float* ah_W      = (const float*)d_in[9];
    const float* ah_b      = (const float*)d_in[10];
    const float* ao_W      = (const float*)d_in[11];
    const float* ao_b      = (const float*)d_in[12];
    const float* gru_Wih   = (const float*)d_in[13];  // [8,3072,1024]
    const float* gru_Whh   = (const float*)d_in[14];  // [8,3072,1024]
    const float* gru_bih   = (const float*)d_in[15];  // [8,3072]
    const float* gru_bhh   = (const float*)d_in[16];  // [8,3072]
    const float* out_W     = (const float*)d_in[17];  // [32000,1024]
    const float* out_b     = (const float*)d_in[18];  // [32000]

    float* out      = (float*)d_out;
    float* out_logp = out;                    // [64,32000]
    float* out_h1   = out + 2048000;          // [64,1024]
    float* out_nh   = out + 2048000 + 65536;  // [8,64,1024]

    float* w = (float*)d_ws;                  // fp32 accumulators (element offsets)
    float* t0    = w + 0;        // [64,1024]
    float* a1b   = w + 65536;
    float* a2b   = w + 131072;
    float* attnb = w + 196608;
    float* gh    = w + 262144;   // [8,64,3072]
    float* gi    = w + 1835008;  // [8,64,3072]
    float* stats = w + 3407872;  // [64]
    // bf16 A-operand buffers
    __bf16* xin   = (__bf16*)(w + 3407936);  // [64,1024]
    __bf16* featb = (__bf16*)(w + 3440704);  // [64,2048]
    __bf16* a1A   = (__bf16*)(w + 3506240);  // [64,1024]
    __bf16* a2A   = (__bf16*)(w + 3539008);
    __bf16* a3A   = (__bf16*)(w + 3571776);
    __bf16* hbf   = (__bf16*)(w + 3604544);  // [8,64,1024]

    // bias pre-init of all fp32 accumulators
    init_acc<<<21312, 256, 0, stream>>>(map_b, ai_b, ah_b, ao_b,
                                        gru_bhh, gru_bih, out_b,
                                        t0, a1b, a2b, attnb, gh, gi, out_logp);
    // xe = bf16(relu(emb[x]))
    gather_relu<<<64, 256, 0, stream>>>(emb, x, xin);
    // featb = bf16(feature)
    conv_bf<0, 0><<<128, 256, 0, stream>>>(feature, nullptr, featb, 32768);

    // t0 += featb @ map_W.T   (K=2048, 16 chunks of 128)
    gemm_acc<<<dim3(16, 16, 1), 256, 0, stream>>>(featb, 0, map_W, 0,
                                                  t0, 0, 2048, 128, 1024);
    // a1A = bf16(relu(t0) + attention)   (matches ref: feat+attention)
    conv_bf<1, 1><<<64, 256, 0, stream>>>(t0, attention, a1A, 16384);
    gemm_acc<<<dim3(16, 8, 1), 256, 0, stream>>>(a1A, 0, ai_W, 0,
                                                 a1b, 0, 1024, 128, 1024);
    conv_bf<1, 0><<<64, 256, 0, stream>>>(a1b, nullptr, a2A, 16384);
    gemm_acc<<<dim3(16, 8, 1), 256, 0, stream>>>(a2A, 0, ah_W, 0,
                                                 a2b, 0, 1024, 128, 1024);
    conv_bf<1, 0><<<64, 256, 0, stream>>>(a2b, nullptr, a3A, 16384);
    gemm_acc<<<dim3(16, 8, 1), 256, 0, stream>>>(a3A, 0, ao_W, 0,
                                                 attnb, 0, 1024, 128, 1024);

    // hbf[i] = bf16(hiddens[i] + relu(attn))
    hsum<<<512, 256, 0, stream>>>(hiddens, attnb, hbf);

    // batched gh[i] += hbf[i] @ Whh[i].T   (8 layers x 2 k-chunks)
    gemm_acc<<<dim3(48, 2, 8), 256, 0, stream>>>(hbf, 65536, gru_Whh, 3145728,
                                                 gh, 196608, 1024, 512, 3072);

    // sequential GRU chain (gi k-split 8-way)
    for (int c = 0; c < 8; ++c) {
        gemm_acc<<<dim3(48, 8, 1), 256, 0, stream>>>(
            xin, 0, gru_Wih + (long long)c * 3145728, 0,
            gi + (long long)c * 196608, 0, 1024, 128, 3072);
        gru_pw<<<256, 256, 0, stream>>>(
            gi + (long long)c * 196608, gh + (long long)c * 196608,
            hiddens + (long long)c * 65536, attnb,
            (c >= 2 && c < 7) ? out_nh + (long long)(c - 1) * 65536 : nullptr,
            out_nh + (long long)c * 65536,
            (c == 0) ? out_h1 : nullptr,
            xin);   // c==7: xin = bf16(x8), the out-GEMM A operand
    }

    // logits += x8 @ out_W.T   (500 n-blocks x 2 k-chunks)
    gemm_acc<<<dim3(500, 2, 1), 256, 0, stream>>>(xin, 0, out_W, 0,
                                                  out_logp, 0, 1024, 512, 32000);

    // log_softmax in place
    rowstats<<<64, 256, 0, stream>>>(out_logp, stats);
    logp_k<<<dim3(125, 64), 256, 0, stream>>>(out_logp, stats);
}